// Round 2
// baseline (1159.416 us; speedup 1.0000x reference)
//
#include <hip/hip_runtime.h>

// Problem constants
#define KC 1024          // num codes
#define DD 256           // embedding dim
#define NP 131072        // B*H*W points
#define HWSZ 4096        // H*W
#define TOTZ 33554432    // B*D*H*W

// d_out float offsets (tuple concat: quantized, loss, indices, cluster_size, ema_emb)
#define OUT_Q    0
#define OUT_LOSS 33554432
#define OUT_IDX  33554433
#define OUT_CS   33685505
#define OUT_EMA  33686529

// workspace float offsets
#define WS_IDX    0         // int[131072]
#define WS_COUNTS 131072    // float[1024]
#define WS_RCNT   132096    // int[1]  (memset together with counts: 1025 floats)
#define WS_LOSSP  132352    // float[256]
#define WS_ENORM  132608    // float[1024]
#define WS_RLIST  133632    // int[131072]
#define WS_EAUG   264704    // ushort[786432] = 393216 floats (8 cc x 12 ks x 16KB)
#define WS_NEED_FLOATS (WS_EAUG + 393216)

#define MARGIN 0.0625f
#define RTILE 16

typedef __attribute__((ext_vector_type(8))) short bf16x8;
typedef __attribute__((ext_vector_type(4))) float f32x4;

__device__ inline unsigned short f2bf_rne(float x) {
    unsigned u = __float_as_uint(x);
    unsigned r = u + 0x7FFFu + ((u >> 16) & 1u);
    return (unsigned short)(r >> 16);
}
__device__ inline float bf2f(unsigned short h) {
    return __uint_as_float(((unsigned)h) << 16);
}
// monotone float->uint, packed with code index: min key = min dist, tie -> min idx
__device__ inline unsigned long long packkey(float d, int c) {
    unsigned u = __float_as_uint(d);
    u = (u & 0x80000000u) ? ~u : (u | 0x80000000u);
    return (((unsigned long long)u) << 32) | (unsigned)c;
}

__global__ __launch_bounds__(256) void enorm_kernel(const float* __restrict__ emb,
                                                    float* __restrict__ enorm) {
    const int k = blockIdx.x;
    float v = emb[k * DD + threadIdx.x];
    v *= v;
    #pragma unroll
    for (int off = 32; off > 0; off >>= 1) v += __shfl_down(v, off);
    __shared__ float red[4];
    if ((threadIdx.x & 63) == 0) red[threadIdx.x >> 6] = v;
    __syncthreads();
    if (threadIdx.x == 0) enorm[k] = (red[0] + red[1]) + (red[2] + red[3]);
}

// emb_aug: [cc(8)][ks(12)][kc(2)][nt(8)][lane(64)][8 bf16]; ks 0..7 = hi, 8..11 = mid
__global__ __launch_bounds__(256) void convert_emb_kernel(
    const float* __restrict__ emb, unsigned short* __restrict__ eaug)
{
    const int blk = blockIdx.x;            // cc*12 + ks
    const int cc = blk / 12, ks = blk % 12;
    const int mode = (ks >= 8);
    unsigned short* outp = eaug + (size_t)blk * 8192;
    #pragma unroll
    for (int i = 0; i < 4; ++i) {
        const int f = i * 256 + threadIdx.x;
        const int kc = f >> 9, nt = (f >> 6) & 7, lane = f & 63;
        const int q = lane >> 4, col = lane & 15;
        const int n = cc * 128 + nt * 16 + col;
        const int k0 = ((ks * 64) & 255) + kc * 32 + q * 8;
        const float* src = emb + (size_t)n * 256 + k0;
        unsigned short v[8];
        #pragma unroll
        for (int j = 0; j < 8; ++j) {
            const float x = src[j];
            const unsigned short h = f2bf_rne(x);
            v[j] = mode ? f2bf_rne(x - bf2f(h)) : h;
        }
        *(uint4*)(outp + (size_t)f * 8) = *(uint4*)v;
    }
}

// MFMA GEMM + fused argmin + fused z->bf16 conversion.
// Block: 64 points x 1024 codes, 256 threads = 4 waves, 64 KB LDS -> 2 blocks/CU.
// The two resident blocks are independent instruction streams (no shared
// barriers), so one block's staging/VALU overlaps the other's MFMA.
// Staging: z fp32 is read directly (transpose-gather, 64B segments), converted
// to hi+mid bf16 fragments with the SAME f2bf_rne math as the old convert_z
// kernel (bitwise-identical fragments), written to LDS once. Main loop is
// ZERO-barrier: B (eaug, L2-hot) register-prefetched one ks ahead; j-loop
// fully unrolled (no bcur moves, immediate-folded addresses); setprio(1)
// around each 16-MFMA cluster (T5: two drifting blocks = role diversity).
// MFMA order per acc: hi*hi ks0-3, hi*mid ks8-11, mid*hi ks4-7 (unchanged).
__global__ __launch_bounds__(256, 2) void gemm_argmin_kernel(
    const float* __restrict__ z, const unsigned short* __restrict__ eaug,
    const float* __restrict__ enorm, int* __restrict__ idx_out,
    float* __restrict__ idx_out_f, float* __restrict__ counts,
    int* __restrict__ rcnt, int* __restrict__ rlist)
{
    __shared__ float smem[16384];                 // 64 KB: 8 A slabs of 8 KB
    unsigned short* aS = (unsigned short*)smem;   // slab s: s*4096 halfwords
    const int t = threadIdx.x, w = t >> 6, lane = t & 63;
    const int nq = w;                             // wave = 64 pts x 64 codes
    const int col = lane & 15;
    const int pt = blockIdx.x;                    // 2048 tiles of 64 points

    // ---- fused staging: 2048 fragment-jobs (kslot x kc x mt x lane), 8/thread
    #pragma unroll
    for (int jj0 = 0; jj0 < 8; ++jj0) {
        const int jj = jj0 * 256 + t;
        const int kslot = jj >> 9;                // 0..3
        const int r = jj & 511;
        const int kc = r >> 8, mt = (r >> 6) & 3, lf = r & 63;
        const int q = lf >> 4, cl = lf & 15;
        const int p = pt * 64 + mt * 16 + cl;
        const int b = p >> 12, hw = p & 4095;
        const int k0 = kslot * 64 + kc * 32 + q * 8;
        const float* src = z + (size_t)b * 1048576 + (size_t)k0 * 4096 + hw;
        unsigned short vh[8], vm[8];
        #pragma unroll
        for (int i = 0; i < 8; ++i) {
            const float x = src[i * 4096];
            const unsigned short h = f2bf_rne(x);
            vh[i] = h;
            vm[i] = f2bf_rne(x - bf2f(h));
        }
        const int off = kc * 2048 + mt * 512 + lf * 8;
        *(uint4*)(aS + kslot * 4096 + off) = *(uint4*)vh;        // hi slabs 0-3
        *(uint4*)(aS + (4 + kslot) * 4096 + off) = *(uint4*)vm;  // mid slabs 4-7
    }

    float rb[16], rs[16]; int ri[16];
    #pragma unroll
    for (int s = 0; s < 16; ++s) { rb[s] = 3.4e38f; rs[s] = 3.4e38f; ri[s] = 0; }

    __syncthreads();                              // all fragments resident

    #pragma unroll 1
    for (int g = 0; g < 4; ++g) {
        const int ccg = g * 2 + (nq >> 1);
        const int nbase = ccg * 128 + (nq & 1) * 64;
        const unsigned short* eb = eaug + (size_t)ccg * (12 * 8192)
                                 + (nq & 1) * 2048 + (size_t)lane * 8;
        f32x4 acc[4][4];
        #pragma unroll
        for (int mi = 0; mi < 4; ++mi)
            #pragma unroll
            for (int ni = 0; ni < 4; ++ni) acc[mi][ni] = (f32x4){0.f, 0.f, 0.f, 0.f};
        float en[4];
        #pragma unroll
        for (int ni = 0; ni < 4; ++ni) en[ni] = enorm[nbase + ni * 16 + col];

        bf16x8 bcur[2][4], bnxt[2][4];
        #pragma unroll
        for (int kc = 0; kc < 2; ++kc)
            #pragma unroll
            for (int ni = 0; ni < 4; ++ni)
                bcur[kc][ni] = *(const bf16x8*)(eb + kc * 4096 + ni * 512);   // ks=0

        #pragma unroll
        for (int j = 0; j < 12; ++j) {
            const int slab = (j < 8) ? (j & 3) : (4 + (j & 3));
            if (j < 11) {
                const int jn = j + 1;
                const int ksn = (jn < 4) ? jn : ((jn < 8) ? jn + 4 : jn - 4);
                const unsigned short* ebk = eb + (size_t)ksn * 8192;
                #pragma unroll
                for (int kc = 0; kc < 2; ++kc)
                    #pragma unroll
                    for (int ni = 0; ni < 4; ++ni)
                        bnxt[kc][ni] = *(const bf16x8*)(ebk + kc * 4096 + ni * 512);
            }
            #pragma unroll
            for (int kc = 0; kc < 2; ++kc) {
                bf16x8 af[4];
                #pragma unroll
                for (int mi = 0; mi < 4; ++mi)
                    af[mi] = *(const bf16x8*)(aS + slab * 4096 + kc * 2048
                                              + mi * 512 + lane * 8);
                __builtin_amdgcn_s_setprio(1);
                #pragma unroll
                for (int mi = 0; mi < 4; ++mi)
                    #pragma unroll
                    for (int ni = 0; ni < 4; ++ni)
                        acc[mi][ni] = __builtin_amdgcn_mfma_f32_16x16x32_bf16(
                            af[mi], bcur[kc][ni], acc[mi][ni], 0, 0, 0);
                __builtin_amdgcn_s_setprio(0);
            }
            if (j < 11) {
                #pragma unroll
                for (int kc = 0; kc < 2; ++kc)
                    #pragma unroll
                    for (int ni = 0; ni < 4; ++ni)
                        bcur[kc][ni] = bnxt[kc][ni];
            }
        }
        // epilogue: dist = enorm - 2*dot; per-slot (min, 2nd, idx) over 4 ni, merge
        #pragma unroll
        for (int mi = 0; mi < 4; ++mi) {
            #pragma unroll
            for (int r = 0; r < 4; ++r) {
                const int s = mi * 4 + r;
                float v0 = fmaf(-2.f, acc[mi][0][r], en[0]);
                float v1 = fmaf(-2.f, acc[mi][1][r], en[1]);
                float v2 = fmaf(-2.f, acc[mi][2][r], en[2]);
                float v3 = fmaf(-2.f, acc[mi][3][r], en[3]);
                const int nb = nbase + col;
                float b01 = fminf(v0, v1), x01 = fmaxf(v0, v1);
                int   i01 = (v1 < v0) ? nb + 16 : nb;
                float b23 = fminf(v2, v3), x23 = fmaxf(v2, v3);
                int   i23 = (v3 < v2) ? nb + 48 : nb + 32;
                float b = fminf(b01, b23);
                int   ib = (b23 < b01) ? i23 : i01;
                float s2 = fminf(fmaxf(b01, b23), fminf(x01, x23));
                if (b < rb[s]) { rs[s] = fminf(rb[s], s2); rb[s] = b; ri[s] = ib; }
                else           { rs[s] = fminf(rs[s], b); }
            }
        }
    }

    // dump (4 waves x 16 slots x 64 lanes = 48 KB, aliases A slabs) + reduce
    __syncthreads();                              // all A reads complete
    float* rbS = smem;                 // [4][16][64]
    float* rsS = smem + 4096;
    int*   riS = (int*)(smem + 8192);
    #pragma unroll
    for (int s = 0; s < 16; ++s) {
        rbS[w * 1024 + s * 64 + lane] = rb[s];
        rsS[w * 1024 + s * 64 + lane] = rs[s];
        riS[w * 1024 + s * 64 + lane] = ri[s];
    }
    __syncthreads();
    if (t < 64) {
        const int r = t;                          // point row in tile
        const int mi = r >> 4, q = (r >> 2) & 3, rr = r & 3;
        const int s = mi * 4 + rr;
        float B = 3.4e38f, S = 3.4e38f; int I = 0;
        #pragma unroll
        for (int wv = 0; wv < 4; ++wv) {
            const int base = wv * 1024 + s * 64 + q * 16;
            #pragma unroll
            for (int ln = 0; ln < 16; ++ln) {
                const float b = rbS[base + ln];
                const float s2 = rsS[base + ln];
                const int   i = riS[base + ln];
                if (b < B) { S = fminf(B, s2); B = b; I = i; }
                else       { S = fminf(S, b); }
            }
        }
        const int p = pt * 64 + r;
        idx_out[p] = I;
        idx_out_f[p] = (float)I;
        atomicAdd(&counts[I], 1.0f);
        if (S - B < MARGIN) {
            const int pos = atomicAdd(rcnt, 1);
            rlist[pos] = p;
        }
    }
}

// Batched exact fp32 re-argmin: 16 points staged in LDS, each thread owns 4
// codes (c = ci*256 + t) with dot[16][4] register accumulators -> per d4 only
// 16 LDS reads + 4 e-loads for 256 FMA. Numerics identical to prior version.
__global__ __launch_bounds__(256) void rescue_kernel(
    const float* __restrict__ z, const float* __restrict__ emb,
    const float* __restrict__ enorm, const int* __restrict__ rcnt,
    const int* __restrict__ rlist, int* __restrict__ idx_out,
    float* __restrict__ idx_out_f, float* __restrict__ counts)
{
    __shared__ float zl[RTILE][DD];
    __shared__ unsigned long long lkey[RTILE];
    const int n = *rcnt;
    if (n <= 0) return;
    const int ntiles = (n + RTILE - 1) / RTILE;
    const int t = threadIdx.x;
    const int slot = t & 15, drow = t >> 4;    // thread loads 16 dims for one slot
    #pragma unroll 1
    for (int tile = blockIdx.x; tile < ntiles; tile += gridDim.x) {
        const int base = tile * RTILE;
        {
            const int ridx = min(base + slot, n - 1);   // clamp: dup compute, guarded update
            const int p = rlist[ridx];
            const int b = p >> 12, hw = p & 4095;
            const float* zp = z + (size_t)b * 1048576 + hw;
            #pragma unroll
            for (int j = 0; j < 16; ++j)
                zl[slot][drow * 16 + j] = zp[(size_t)(drow * 16 + j) * 4096];
        }
        if (t < RTILE) lkey[t] = ~0ull;
        __syncthreads();
        float dot[RTILE][4];
        #pragma unroll
        for (int p = 0; p < RTILE; ++p)
            #pragma unroll
            for (int ci = 0; ci < 4; ++ci) dot[p][ci] = 0.f;
        #pragma unroll 1
        for (int d4 = 0; d4 < 64; ++d4) {
            float4 ev[4];
            #pragma unroll
            for (int ci = 0; ci < 4; ++ci)
                ev[ci] = *(const float4*)(emb + (size_t)(ci * 256 + t) * 256 + d4 * 4);
            #pragma unroll
            for (int p = 0; p < RTILE; ++p) {
                const float4 zv = *(const float4*)(&zl[p][d4 * 4]);
                #pragma unroll
                for (int ci = 0; ci < 4; ++ci) {
                    dot[p][ci] = fmaf(zv.x, ev[ci].x, dot[p][ci]);
                    dot[p][ci] = fmaf(zv.y, ev[ci].y, dot[p][ci]);
                    dot[p][ci] = fmaf(zv.z, ev[ci].z, dot[p][ci]);
                    dot[p][ci] = fmaf(zv.w, ev[ci].w, dot[p][ci]);
                }
            }
        }
        float en[4];
        #pragma unroll
        for (int ci = 0; ci < 4; ++ci) en[ci] = enorm[ci * 256 + t];
        #pragma unroll
        for (int p = 0; p < RTILE; ++p) {
            unsigned long long k = packkey(fmaf(-2.f, dot[p][0], en[0]), t);
            #pragma unroll
            for (int ci = 1; ci < 4; ++ci) {
                const unsigned long long k2 =
                    packkey(fmaf(-2.f, dot[p][ci], en[ci]), ci * 256 + t);
                k = (k2 < k) ? k2 : k;
            }
            atomicMin(&lkey[p], k);
        }
        __syncthreads();
        if (t < RTILE && base + t < n) {
            const int p = rlist[base + t];
            const int fc = (int)(lkey[t] & 0xFFFFFFFFull);
            const int old = idx_out[p];
            if (fc != old) {
                atomicAdd(&counts[old], -1.0f);
                atomicAdd(&counts[fc], 1.0f);
                idx_out[p] = fc;
                idx_out_f[p] = (float)fc;
            }
        }
        __syncthreads();
    }
}

// Fused quantize + dw-segment-sum + loss. Block = one dim d (256 blocks x 512 thr).
__global__ __launch_bounds__(512) void dwq_kernel(
    const float* __restrict__ z, const float* __restrict__ emb,
    const int* __restrict__ idx, const float* __restrict__ ema_emb,
    float* __restrict__ out_q, float* __restrict__ out_ema,
    float* __restrict__ lossp)
{
    __shared__ float kdw[KC];
    __shared__ float ecol[KC];
    __shared__ float red[8];
    const int d = blockIdx.x;
    const int t = threadIdx.x;
    #pragma unroll
    for (int k = t; k < KC; k += 512) { kdw[k] = 0.f; ecol[k] = emb[(size_t)k * 256 + d]; }
    __syncthreads();
    float ls = 0.f;
    #pragma unroll 1
    for (int it = 0; it < 64; ++it) {
        const int e = it * 512 + t;            // float4-unit over (b, hw)
        const int b = e >> 10, hwi = (e & 1023) << 2;
        const size_t zoff = (size_t)b * 1048576 + (size_t)d * 4096 + hwi;
        const float4 zv = *(const float4*)(z + zoff);
        const int4 iv = *(const int4*)(idx + b * 4096 + hwi);
        const float q0 = ecol[iv.x], q1 = ecol[iv.y], q2 = ecol[iv.z], q3 = ecol[iv.w];
        float4 qv; qv.x = q0; qv.y = q1; qv.z = q2; qv.w = q3;
        *(float4*)(out_q + zoff) = qv;
        atomicAdd(&kdw[iv.x], zv.x);
        atomicAdd(&kdw[iv.y], zv.y);
        atomicAdd(&kdw[iv.z], zv.z);
        atomicAdd(&kdw[iv.w], zv.w);
        const float d0 = zv.x - q0, d1 = zv.y - q1, d2 = zv.z - q2, d3 = zv.w - q3;
        ls += (d0 * d0 + d1 * d1) + (d2 * d2 + d3 * d3);
    }
    __syncthreads();
    #pragma unroll
    for (int k = t; k < KC; k += 512)
        out_ema[(size_t)k * 256 + d] = 0.99f * ema_emb[(size_t)k * 256 + d] + 0.01f * kdw[k];
    #pragma unroll
    for (int off = 32; off > 0; off >>= 1) ls += __shfl_down(ls, off);
    if ((t & 63) == 0) red[t >> 6] = ls;
    __syncthreads();
    if (t == 0) {
        float s = 0.f;
        #pragma unroll
        for (int i = 0; i < 8; ++i) s += red[i];
        lossp[blockIdx.x] = s;
    }
}

__global__ __launch_bounds__(256) void finalize_kernel(
    const float* __restrict__ ema_cs, const float* __restrict__ counts,
    const float* __restrict__ lossp, float* __restrict__ out)
{
    const int i = blockIdx.x * 256 + threadIdx.x;   // 4 blocks
    out[OUT_CS + i] = 0.99f * ema_cs[i] + 0.01f * counts[i];
    if (blockIdx.x == 0) {
        float s = lossp[threadIdx.x];
        #pragma unroll
        for (int off = 32; off > 0; off >>= 1) s += __shfl_down(s, off);
        __shared__ float red[4];
        if ((threadIdx.x & 63) == 0) red[threadIdx.x >> 6] = s;
        __syncthreads();
        if (threadIdx.x == 0)
            out[OUT_LOSS] = 0.25f * ((red[0] + red[1]) + (red[2] + red[3])) / 33554432.0f;
    }
}

// ---------- fallback fp32 GEMM (used if ws too small) ----------
__global__ __launch_bounds__(256) void dist_argmin_kernel(
    const float* __restrict__ z, const float* __restrict__ emb,
    const float* __restrict__ enorm, int* __restrict__ idx_out,
    float* __restrict__ idx_out_f, float* __restrict__ counts)
{
    __shared__ float smem[4096];
    float* As = smem;
    float* Bs = smem + 1024;
    const int tid = threadIdx.x;
    const int tx = tid & 15, ty = tid >> 4;
    const int p0 = blockIdx.x * 128;
    const int b = p0 >> 12, hw0 = p0 & 4095;
    const float* zb = z + (size_t)b * (DD * HWSZ) + hw0;
    const int arow = (tid & 31) * 4, akd = tid >> 5;
    const int bcode = tid >> 1, bj = (tid & 1) * 4;
    float best[8]; int bidx[8];
    #pragma unroll
    for (int i = 0; i < 8; i++) { best[i] = 3.4e38f; bidx[i] = 0; }
    #pragma unroll 1
    for (int cc = 0; cc < 8; ++cc) {
        const int c0 = cc * 128;
        float acc[8][8];
        #pragma unroll
        for (int i = 0; i < 8; i++)
            #pragma unroll
            for (int j = 0; j < 8; j++) acc[i][j] = 0.0f;
        #pragma unroll 1
        for (int dk = 0; dk < 32; ++dk) {
            const int kk0 = dk * 8;
            const float4 av = *(const float4*)(zb + (kk0 + akd) * HWSZ + arow);
            const float4 bv = *(const float4*)(emb + (c0 + bcode) * DD + kk0 + bj);
            __syncthreads();
            *(float4*)(As + akd * 128 + arow) = av;
            Bs[(bj + 0) * 128 + bcode] = bv.x;
            Bs[(bj + 1) * 128 + bcode] = bv.y;
            Bs[(bj + 2) * 128 + bcode] = bv.z;
            Bs[(bj + 3) * 128 + bcode] = bv.w;
            __syncthreads();
            #pragma unroll
            for (int kk = 0; kk < 8; ++kk) {
                const float4 a0 = *(const float4*)(As + kk * 128 + ty * 8);
                const float4 a1 = *(const float4*)(As + kk * 128 + ty * 8 + 4);
                const float4 b0 = *(const float4*)(Bs + kk * 128 + tx * 8);
                const float4 b1 = *(const float4*)(Bs + kk * 128 + tx * 8 + 4);
                const float a[8] = {a0.x,a0.y,a0.z,a0.w,a1.x,a1.y,a1.z,a1.w};
                const float bb[8] = {b0.x,b0.y,b0.z,b0.w,b1.x,b1.y,b1.z,b1.w};
                #pragma unroll
                for (int i = 0; i < 8; i++)
                    #pragma unroll
                    for (int j = 0; j < 8; j++)
                        acc[i][j] = fmaf(a[i], bb[j], acc[i][j]);
            }
        }
        const float4 en0 = *(const float4*)(enorm + c0 + tx * 8);
        const float4 en1 = *(const float4*)(enorm + c0 + tx * 8 + 4);
        const float en[8] = {en0.x,en0.y,en0.z,en0.w,en1.x,en1.y,en1.z,en1.w};
        #pragma unroll
        for (int j = 0; j < 8; j++) {
            const int c = c0 + tx * 8 + j;
            #pragma unroll
            for (int i = 0; i < 8; i++) {
                const float dist = fmaf(-2.0f, acc[i][j], en[j]);
                if (dist < best[i]) { best[i] = dist; bidx[i] = c; }
            }
        }
    }
    __syncthreads();
    float* rmin = smem;
    int* ridx = (int*)(smem + 2048);
    #pragma unroll
    for (int i = 0; i < 8; i++) {
        const int r = ty * 8 + i;
        rmin[r * 16 + tx] = best[i];
        ridx[r * 16 + tx] = bidx[i];
    }
    __syncthreads();
    if (tid < 128) {
        const int r = tid;
        float m = rmin[r * 16]; int mi = ridx[r * 16];
        #pragma unroll
        for (int tt = 1; tt < 16; tt++) {
            const float v = rmin[r * 16 + tt];
            const int vi = ridx[r * 16 + tt];
            if (v < m || (v == m && vi < mi)) { m = v; mi = vi; }
        }
        const int p = p0 + r;
        idx_out[p] = mi;
        idx_out_f[p] = (float)mi;
        atomicAdd(&counts[mi], 1.0f);
    }
}

extern "C" void kernel_launch(void* const* d_in, const int* in_sizes, int n_in,
                              void* d_out, int out_size, void* d_ws, size_t ws_size,
                              hipStream_t stream) {
    const float* z       = (const float*)d_in[0];
    const float* emb     = (const float*)d_in[1];
    const float* ema_cs  = (const float*)d_in[2];
    const float* ema_emb = (const float*)d_in[3];
    float* out = (float*)d_out;
    float* ws  = (float*)d_ws;

    int*   ws_idx    = (int*)(ws + WS_IDX);
    float* ws_counts = ws + WS_COUNTS;
    int*   ws_rcnt   = (int*)(ws + WS_RCNT);
    float* ws_lossp  = ws + WS_LOSSP;
    float* ws_enorm  = ws + WS_ENORM;
    int*   ws_rlist  = (int*)(ws + WS_RLIST);
    unsigned short* ws_eaug = (unsigned short*)(ws + WS_EAUG);

    // zero counts + rescue counter
    hipMemsetAsync(ws_counts, 0, 1025 * sizeof(float), stream);
    hipLaunchKernelGGL(enorm_kernel, dim3(KC), dim3(256), 0, stream, emb, ws_enorm);

    if (ws_size >= (size_t)WS_NEED_FLOATS * sizeof(float)) {
        hipLaunchKernelGGL(convert_emb_kernel, dim3(96), dim3(256), 0, stream, emb, ws_eaug);
        hipLaunchKernelGGL(gemm_argmin_kernel, dim3(2048), dim3(256), 0, stream,
                           z, ws_eaug, ws_enorm, ws_idx, out + OUT_IDX,
                           ws_counts, ws_rcnt, ws_rlist);
        hipLaunchKernelGGL(rescue_kernel, dim3(512), dim3(256), 0, stream,
                           z, emb, ws_enorm, ws_rcnt, ws_rlist,
                           ws_idx, out + OUT_IDX, ws_counts);
    } else {
        hipLaunchKernelGGL(dist_argmin_kernel, dim3(NP / 128), dim3(256), 0, stream,
                           z, emb, ws_enorm, ws_idx, out + OUT_IDX, ws_counts);
    }

    hipLaunchKernelGGL(dwq_kernel, dim3(DD), dim3(512), 0, stream,
                       z, emb, ws_idx, ema_emb, out, out + OUT_EMA, ws_lossp);
    hipLaunchKernelGGL(finalize_kernel, dim3(4), dim3(256), 0, stream,
                       ema_cs, ws_counts, ws_lossp, out);
}

// Round 3
// 741.679 us; speedup vs baseline: 1.5632x; 1.5632x over previous
//
#include <hip/hip_runtime.h>

// Problem constants
#define KC 1024          // num codes
#define DD 256           // embedding dim
#define NP 131072        // B*H*W points
#define HWSZ 4096        // H*W
#define TOTZ 33554432    // B*D*H*W

// d_out float offsets (tuple concat: quantized, loss, indices, cluster_size, ema_emb)
#define OUT_Q    0
#define OUT_LOSS 33554432
#define OUT_IDX  33554433
#define OUT_CS   33685505
#define OUT_EMA  33686529

// workspace float offsets
#define WS_IDX    0         // int[131072]
#define WS_COUNTS 131072    // float[1024]
#define WS_RCNT   132096    // int[1]  (memset together with counts: 1025 floats)
#define WS_LOSSP  132352    // float[256]
#define WS_ENORM  132608    // float[1024]
#define WS_RLIST  133632    // int[131072]
#define WS_EAUG   264704    // ushort[786432] = 393216 floats (8 cc x 12 ks x 16KB)
#define WS_NEED_FLOATS (WS_EAUG + 393216)

#define MARGIN 0.0625f
#define RTILE 16

typedef __attribute__((ext_vector_type(8))) short bf16x8;
typedef __attribute__((ext_vector_type(4))) float f32x4;

__device__ inline unsigned short f2bf_rne(float x) {
    unsigned u = __float_as_uint(x);
    unsigned r = u + 0x7FFFu + ((u >> 16) & 1u);
    return (unsigned short)(r >> 16);
}
__device__ inline float bf2f(unsigned short h) {
    return __uint_as_float(((unsigned)h) << 16);
}
// monotone float->uint, packed with code index: min key = min dist, tie -> min idx
__device__ inline unsigned long long packkey(float d, int c) {
    unsigned u = __float_as_uint(d);
    u = (u & 0x80000000u) ? ~u : (u | 0x80000000u);
    return (((unsigned long long)u) << 32) | (unsigned)c;
}

__global__ __launch_bounds__(256) void enorm_kernel(const float* __restrict__ emb,
                                                    float* __restrict__ enorm) {
    const int k = blockIdx.x;
    float v = emb[k * DD + threadIdx.x];
    v *= v;
    #pragma unroll
    for (int off = 32; off > 0; off >>= 1) v += __shfl_down(v, off);
    __shared__ float red[4];
    if ((threadIdx.x & 63) == 0) red[threadIdx.x >> 6] = v;
    __syncthreads();
    if (threadIdx.x == 0) enorm[k] = (red[0] + red[1]) + (red[2] + red[3]);
}

// emb_aug: [cc(8)][ks(12)][kc(2)][nt(8)][lane(64)][8 bf16]; ks 0..3 hi, 8..11 mid.
// ks 4..7 (the old hi-dup pass) are no longer read -> only 8 ks generated.
__global__ __launch_bounds__(256) void convert_emb_kernel(
    const float* __restrict__ emb, unsigned short* __restrict__ eaug)
{
    const int blk = blockIdx.x;            // cc*8 + ks'
    const int cc = blk >> 3, ksp = blk & 7;
    const int ks = ksp + ((ksp >= 4) ? 4 : 0);   // {0,1,2,3,8,9,10,11}
    const int mode = (ks >= 8);
    unsigned short* outp = eaug + (size_t)(cc * 12 + ks) * 8192;
    #pragma unroll
    for (int i = 0; i < 4; ++i) {
        const int f = i * 256 + threadIdx.x;
        const int kc = f >> 9, nt = (f >> 6) & 7, lane = f & 63;
        const int q = lane >> 4, col = lane & 15;
        const int n = cc * 128 + nt * 16 + col;
        const int k0 = ((ks * 64) & 255) + kc * 32 + q * 8;
        const float* src = emb + (size_t)n * 256 + k0;
        unsigned short v[8];
        #pragma unroll
        for (int j = 0; j < 8; ++j) {
            const float x = src[j];
            const unsigned short h = f2bf_rne(x);
            v[j] = mode ? f2bf_rne(x - bf2f(h)) : h;
        }
        *(uint4*)(outp + (size_t)f * 8) = *(uint4*)v;
    }
}

// MFMA GEMM + fused argmin + fused z->bf16 conversion.
// Block: 128 pts x 1024 codes, 512 threads = 8 waves, 152 KB LDS, 1 block/CU.
// B-traffic restructure vs R1 (which was L2-BW-bound on eaug):
//  - mh-dedup: each wave owns 64 codes x ALL 128 pts (acc[8][4]); B read once.
//  - Bh-reuse: 8 steps/g. hi-step s: load Bh[chunk s], run Ah x Bh AND Am x Bh.
//    mid-step s: load Bm[chunk s-4], run Ah x Bm. (zh*eh + zm*eh + zh*em.)
//  Per-block B bytes: 3 MB -> 1 MB.
// Register budget (cap 256 via launch_bounds(512,2)): acc 128 + b0/b1/bn 48 +
// af 32 + addr ~20. Argmin epilogue per g: shfl_xor col-reduce -> 12 B/pt dump
// to LDS (no persistent rb/rs/ri regs). Main loop has ZERO barriers.
__global__ __launch_bounds__(512, 2) void gemm_argmin_kernel(
    const float* __restrict__ z, const unsigned short* __restrict__ eaug,
    const float* __restrict__ enorm, int* __restrict__ idx_out,
    float* __restrict__ idx_out_f, float* __restrict__ counts,
    int* __restrict__ rcnt, int* __restrict__ rlist)
{
    __shared__ float smem[39296];                 // 128KB A slabs + 25.5KB dump
    unsigned short* aS = (unsigned short*)smem;   // 8 slabs x 8192 hw (hi 0-3, mid 4-7)
    float* dumpB = smem + 32768;                  // [128][17]
    float* dumpS = smem + 32768 + 2176;
    int*   dumpI = (int*)(smem + 32768 + 4352);
    const int t = threadIdx.x, w = t >> 6, lane = t & 63;
    const int q = lane >> 4, col = lane & 15;
    const int pt = blockIdx.x;                    // 1024 tiles of 128 points

    // ---- fused staging: 4096 fragment jobs (kslot4 x kc2 x mt8 x lf64), 8/thread
    #pragma unroll 2
    for (int jj0 = 0; jj0 < 8; ++jj0) {
        const int jj = jj0 * 512 + t;
        const int kslot = jj >> 10;
        const int r = jj & 1023;
        const int kc = r >> 9, mt = (r >> 6) & 7, lf = r & 63;
        const int qq = lf >> 4, cl = lf & 15;
        const int p = pt * 128 + mt * 16 + cl;
        const int b = p >> 12, hw = p & 4095;
        const int k0 = kslot * 64 + kc * 32 + qq * 8;
        const float* src = z + (size_t)b * 1048576 + (size_t)k0 * 4096 + hw;
        unsigned short vh[8], vm[8];
        #pragma unroll
        for (int i = 0; i < 8; ++i) {
            const float x = src[i * 4096];
            const unsigned short h = f2bf_rne(x);
            vh[i] = h;
            vm[i] = f2bf_rne(x - bf2f(h));
        }
        const int off = kc * 4096 + mt * 512 + lf * 8;
        *(uint4*)(aS + kslot * 8192 + off) = *(uint4*)vh;        // hi slab
        *(uint4*)(aS + (4 + kslot) * 8192 + off) = *(uint4*)vm;  // mid slab
    }
    __syncthreads();                              // all 8 slabs resident

#define MFMA_SET(BREG, KCI)                                                   \
    {                                                                         \
        bf16x8 af[8];                                                         \
        _Pragma("unroll")                                                     \
        for (int mi = 0; mi < 8; ++mi)                                        \
            af[mi] = *(const bf16x8*)(aS + slabH * 8192 + (KCI) * 4096        \
                                      + mi * 512 + lane * 8);                 \
        __builtin_amdgcn_s_setprio(1);                                        \
        _Pragma("unroll")                                                     \
        for (int mi = 0; mi < 8; ++mi)                                        \
            _Pragma("unroll")                                                 \
            for (int ni = 0; ni < 4; ++ni)                                    \
                acc[mi][ni] = __builtin_amdgcn_mfma_f32_16x16x32_bf16(        \
                    af[mi], BREG[ni], acc[mi][ni], 0, 0, 0);                  \
        __builtin_amdgcn_s_setprio(0);                                        \
        if (s < 4) {                                                          \
            _Pragma("unroll")                                                 \
            for (int mi = 0; mi < 8; ++mi)                                    \
                af[mi] = *(const bf16x8*)(aS + (4 + slabH) * 8192             \
                                          + (KCI) * 4096 + mi * 512           \
                                          + lane * 8);                        \
            __builtin_amdgcn_s_setprio(1);                                    \
            _Pragma("unroll")                                                 \
            for (int mi = 0; mi < 8; ++mi)                                    \
                _Pragma("unroll")                                             \
                for (int ni = 0; ni < 4; ++ni)                                \
                    acc[mi][ni] = __builtin_amdgcn_mfma_f32_16x16x32_bf16(    \
                        af[mi], BREG[ni], acc[mi][ni], 0, 0, 0);              \
            __builtin_amdgcn_s_setprio(0);                                    \
        }                                                                     \
    }

    #pragma unroll 1
    for (int g = 0; g < 2; ++g) {
        const int ccg = g * 4 + (w >> 1);
        const int nqh = w & 1;
        const int nbase = g * 512 + w * 64;
        const unsigned short* eb = eaug + (size_t)ccg * 98304 + nqh * 2048
                                 + (size_t)lane * 8;
        float en[4];
        #pragma unroll
        for (int ni = 0; ni < 4; ++ni) en[ni] = enorm[nbase + ni * 16 + col];

        f32x4 acc[8][4];
        #pragma unroll
        for (int mi = 0; mi < 8; ++mi)
            #pragma unroll
            for (int ni = 0; ni < 4; ++ni) acc[mi][ni] = (f32x4){0.f, 0.f, 0.f, 0.f};

        bf16x8 b0[4], b1[4], bn[4];
        #pragma unroll
        for (int ni = 0; ni < 4; ++ni) b0[ni] = *(const bf16x8*)(eb + ni * 512);

        #pragma unroll 1
        for (int s = 0; s < 8; ++s) {
            const int ksE = (s < 4) ? s : (4 + s);      // eaug ks: hi s, mid 8+(s-4)
            const int slabH = (s < 4) ? s : (s - 4);    // A-hi slab = k-chunk
            #pragma unroll
            for (int ni = 0; ni < 4; ++ni)              // this step, kc=1
                b1[ni] = *(const bf16x8*)(eb + ksE * 8192 + 4096 + ni * 512);
            if (s < 7) {                                // next step, kc=0
                const int ksN = (s < 3) ? (s + 1) : ((s == 3) ? 8 : (5 + s));
                #pragma unroll
                for (int ni = 0; ni < 4; ++ni)
                    bn[ni] = *(const bf16x8*)(eb + ksN * 8192 + ni * 512);
            } else if (g == 0) {                        // next g, s=0, kc=0
                const unsigned short* eb1 = eaug + (size_t)(4 + (w >> 1)) * 98304
                                          + nqh * 2048 + (size_t)lane * 8;
                #pragma unroll
                for (int ni = 0; ni < 4; ++ni)
                    bn[ni] = *(const bf16x8*)(eb1 + ni * 512);
            }
            MFMA_SET(b0, 0)
            MFMA_SET(b1, 1)
            if (s < 7 || g == 0) {
                #pragma unroll
                for (int ni = 0; ni < 4; ++ni) b0[ni] = bn[ni];
            }
        }

        // per-g epilogue: dist = en - 2*dot; min/2nd/idx over ni, then over 16 cols
        #pragma unroll
        for (int mi = 0; mi < 8; ++mi) {
            #pragma unroll
            for (int r = 0; r < 4; ++r) {
                float v0 = fmaf(-2.f, acc[mi][0][r], en[0]);
                float v1 = fmaf(-2.f, acc[mi][1][r], en[1]);
                float v2 = fmaf(-2.f, acc[mi][2][r], en[2]);
                float v3 = fmaf(-2.f, acc[mi][3][r], en[3]);
                const int nb = nbase + col;
                float b01 = fminf(v0, v1), x01 = fmaxf(v0, v1);
                int   i01 = (v1 < v0) ? nb + 16 : nb;
                float b23 = fminf(v2, v3), x23 = fmaxf(v2, v3);
                int   i23 = (v3 < v2) ? nb + 48 : nb + 32;
                float b = fminf(b01, b23);
                int   ib = (b23 < b01) ? i23 : i01;
                float s2 = fminf(fmaxf(b01, b23), fminf(x01, x23));
                #pragma unroll
                for (int m = 1; m < 16; m <<= 1) {      // col-group reduce
                    const float ob = __shfl_xor(b, m);
                    const float os = __shfl_xor(s2, m);
                    const int   oi = __shfl_xor(ib, m);
                    const bool sw = ob < b;
                    const float cand = sw ? b : ob;     // loser's best
                    const float osel = sw ? os : s2;    // winner's 2nd
                    b  = sw ? ob : b;
                    ib = sw ? oi : ib;
                    s2 = fminf(cand, osel);
                }
                if (col == 0) {
                    const int pl = mi * 16 + q * 4 + r;
                    const int e = w * 2 + g;
                    dumpB[pl * 17 + e] = b;
                    dumpS[pl * 17 + e] = s2;
                    dumpI[pl * 17 + e] = ib;
                }
            }
        }
    }
#undef MFMA_SET

    __syncthreads();                                    // all dumps visible
    if (t < 128) {
        float B = 3.4e38f, S = 3.4e38f; int I = 0;
        #pragma unroll
        for (int e = 0; e < 16; ++e) {
            const float b = dumpB[t * 17 + e];
            const float s2 = dumpS[t * 17 + e];
            const int   i = dumpI[t * 17 + e];
            if (b < B) { S = fminf(B, s2); B = b; I = i; }
            else       { S = fminf(S, b); }
        }
        const int p = pt * 128 + t;
        idx_out[p] = I;
        idx_out_f[p] = (float)I;
        atomicAdd(&counts[I], 1.0f);
        if (S - B < MARGIN) {
            const int pos = atomicAdd(rcnt, 1);
            rlist[pos] = p;
        }
    }
}

// Batched exact fp32 re-argmin: 16 points staged in LDS, each thread owns 4
// codes (c = ci*256 + t) with dot[16][4] register accumulators -> per d4 only
// 16 LDS reads + 4 e-loads for 256 FMA. Numerics identical to prior version.
__global__ __launch_bounds__(256) void rescue_kernel(
    const float* __restrict__ z, const float* __restrict__ emb,
    const float* __restrict__ enorm, const int* __restrict__ rcnt,
    const int* __restrict__ rlist, int* __restrict__ idx_out,
    float* __restrict__ idx_out_f, float* __restrict__ counts)
{
    __shared__ float zl[RTILE][DD];
    __shared__ unsigned long long lkey[RTILE];
    const int n = *rcnt;
    if (n <= 0) return;
    const int ntiles = (n + RTILE - 1) / RTILE;
    const int t = threadIdx.x;
    const int slot = t & 15, drow = t >> 4;    // thread loads 16 dims for one slot
    #pragma unroll 1
    for (int tile = blockIdx.x; tile < ntiles; tile += gridDim.x) {
        const int base = tile * RTILE;
        {
            const int ridx = min(base + slot, n - 1);   // clamp: dup compute, guarded update
            const int p = rlist[ridx];
            const int b = p >> 12, hw = p & 4095;
            const float* zp = z + (size_t)b * 1048576 + hw;
            #pragma unroll
            for (int j = 0; j < 16; ++j)
                zl[slot][drow * 16 + j] = zp[(size_t)(drow * 16 + j) * 4096];
        }
        if (t < RTILE) lkey[t] = ~0ull;
        __syncthreads();
        float dot[RTILE][4];
        #pragma unroll
        for (int p = 0; p < RTILE; ++p)
            #pragma unroll
            for (int ci = 0; ci < 4; ++ci) dot[p][ci] = 0.f;
        #pragma unroll 1
        for (int d4 = 0; d4 < 64; ++d4) {
            float4 ev[4];
            #pragma unroll
            for (int ci = 0; ci < 4; ++ci)
                ev[ci] = *(const float4*)(emb + (size_t)(ci * 256 + t) * 256 + d4 * 4);
            #pragma unroll
            for (int p = 0; p < RTILE; ++p) {
                const float4 zv = *(const float4*)(&zl[p][d4 * 4]);
                #pragma unroll
                for (int ci = 0; ci < 4; ++ci) {
                    dot[p][ci] = fmaf(zv.x, ev[ci].x, dot[p][ci]);
                    dot[p][ci] = fmaf(zv.y, ev[ci].y, dot[p][ci]);
                    dot[p][ci] = fmaf(zv.z, ev[ci].z, dot[p][ci]);
                    dot[p][ci] = fmaf(zv.w, ev[ci].w, dot[p][ci]);
                }
            }
        }
        float en[4];
        #pragma unroll
        for (int ci = 0; ci < 4; ++ci) en[ci] = enorm[ci * 256 + t];
        #pragma unroll
        for (int p = 0; p < RTILE; ++p) {
            unsigned long long k = packkey(fmaf(-2.f, dot[p][0], en[0]), t);
            #pragma unroll
            for (int ci = 1; ci < 4; ++ci) {
                const unsigned long long k2 =
                    packkey(fmaf(-2.f, dot[p][ci], en[ci]), ci * 256 + t);
                k = (k2 < k) ? k2 : k;
            }
            atomicMin(&lkey[p], k);
        }
        __syncthreads();
        if (t < RTILE && base + t < n) {
            const int p = rlist[base + t];
            const int fc = (int)(lkey[t] & 0xFFFFFFFFull);
            const int old = idx_out[p];
            if (fc != old) {
                atomicAdd(&counts[old], -1.0f);
                atomicAdd(&counts[fc], 1.0f);
                idx_out[p] = fc;
                idx_out_f[p] = (float)fc;
            }
        }
        __syncthreads();
    }
}

// Fused quantize + dw-segment-sum + loss. Block = one dim d (256 blocks x 512 thr).
// kdw parity-split (t&1) to halve LDS-atomic same-address serialization.
__global__ __launch_bounds__(512) void dwq_kernel(
    const float* __restrict__ z, const float* __restrict__ emb,
    const int* __restrict__ idx, const float* __restrict__ ema_emb,
    float* __restrict__ out_q, float* __restrict__ out_ema,
    float* __restrict__ lossp)
{
    __shared__ float kdw[2][KC];
    __shared__ float ecol[KC];
    __shared__ float red[8];
    const int d = blockIdx.x;
    const int t = threadIdx.x;
    #pragma unroll
    for (int k = t; k < KC; k += 512) {
        kdw[0][k] = 0.f; kdw[1][k] = 0.f;
        ecol[k] = emb[(size_t)k * 256 + d];
    }
    __syncthreads();
    float* kd = kdw[t & 1];
    float ls = 0.f;
    #pragma unroll 1
    for (int it = 0; it < 64; ++it) {
        const int e = it * 512 + t;            // float4-unit over (b, hw)
        const int b = e >> 10, hwi = (e & 1023) << 2;
        const size_t zoff = (size_t)b * 1048576 + (size_t)d * 4096 + hwi;
        const float4 zv = *(const float4*)(z + zoff);
        const int4 iv = *(const int4*)(idx + b * 4096 + hwi);
        const float q0 = ecol[iv.x], q1 = ecol[iv.y], q2 = ecol[iv.z], q3 = ecol[iv.w];
        float4 qv; qv.x = q0; qv.y = q1; qv.z = q2; qv.w = q3;
        *(float4*)(out_q + zoff) = qv;
        atomicAdd(&kd[iv.x], zv.x);
        atomicAdd(&kd[iv.y], zv.y);
        atomicAdd(&kd[iv.z], zv.z);
        atomicAdd(&kd[iv.w], zv.w);
        const float d0 = zv.x - q0, d1 = zv.y - q1, d2 = zv.z - q2, d3 = zv.w - q3;
        ls += (d0 * d0 + d1 * d1) + (d2 * d2 + d3 * d3);
    }
    __syncthreads();
    #pragma unroll
    for (int k = t; k < KC; k += 512)
        out_ema[(size_t)k * 256 + d] = 0.99f * ema_emb[(size_t)k * 256 + d]
                                     + 0.01f * (kdw[0][k] + kdw[1][k]);
    #pragma unroll
    for (int off = 32; off > 0; off >>= 1) ls += __shfl_down(ls, off);
    if ((t & 63) == 0) red[t >> 6] = ls;
    __syncthreads();
    if (t == 0) {
        float s = 0.f;
        #pragma unroll
        for (int i = 0; i < 8; ++i) s += red[i];
        lossp[blockIdx.x] = s;
    }
}

__global__ __launch_bounds__(256) void finalize_kernel(
    const float* __restrict__ ema_cs, const float* __restrict__ counts,
    const float* __restrict__ lossp, float* __restrict__ out)
{
    const int i = blockIdx.x * 256 + threadIdx.x;   // 4 blocks
    out[OUT_CS + i] = 0.99f * ema_cs[i] + 0.01f * counts[i];
    if (blockIdx.x == 0) {
        float s = lossp[threadIdx.x];
        #pragma unroll
        for (int off = 32; off > 0; off >>= 1) s += __shfl_down(s, off);
        __shared__ float red[4];
        if ((threadIdx.x & 63) == 0) red[threadIdx.x >> 6] = s;
        __syncthreads();
        if (threadIdx.x == 0)
            out[OUT_LOSS] = 0.25f * ((red[0] + red[1]) + (red[2] + red[3])) / 33554432.0f;
    }
}

// ---------- fallback fp32 GEMM (used if ws too small) ----------
__global__ __launch_bounds__(256) void dist_argmin_kernel(
    const float* __restrict__ z, const float* __restrict__ emb,
    const float* __restrict__ enorm, int* __restrict__ idx_out,
    float* __restrict__ idx_out_f, float* __restrict__ counts)
{
    __shared__ float smem[4096];
    float* As = smem;
    float* Bs = smem + 1024;
    const int tid = threadIdx.x;
    const int tx = tid & 15, ty = tid >> 4;
    const int p0 = blockIdx.x * 128;
    const int b = p0 >> 12, hw0 = p0 & 4095;
    const float* zb = z + (size_t)b * (DD * HWSZ) + hw0;
    const int arow = (tid & 31) * 4, akd = tid >> 5;
    const int bcode = tid >> 1, bj = (tid & 1) * 4;
    float best[8]; int bidx[8];
    #pragma unroll
    for (int i = 0; i < 8; i++) { best[i] = 3.4e38f; bidx[i] = 0; }
    #pragma unroll 1
    for (int cc = 0; cc < 8; ++cc) {
        const int c0 = cc * 128;
        float acc[8][8];
        #pragma unroll
        for (int i = 0; i < 8; i++)
            #pragma unroll
            for (int j = 0; j < 8; j++) acc[i][j] = 0.0f;
        #pragma unroll 1
        for (int dk = 0; dk < 32; ++dk) {
            const int kk0 = dk * 8;
            const float4 av = *(const float4*)(zb + (kk0 + akd) * HWSZ + arow);
            const float4 bv = *(const float4*)(emb + (c0 + bcode) * DD + kk0 + bj);
            __syncthreads();
            *(float4*)(As + akd * 128 + arow) = av;
            Bs[(bj + 0) * 128 + bcode] = bv.x;
            Bs[(bj + 1) * 128 + bcode] = bv.y;
            Bs[(bj + 2) * 128 + bcode] = bv.z;
            Bs[(bj + 3) * 128 + bcode] = bv.w;
            __syncthreads();
            #pragma unroll
            for (int kk = 0; kk < 8; ++kk) {
                const float4 a0 = *(const float4*)(As + kk * 128 + ty * 8);
                const float4 a1 = *(const float4*)(As + kk * 128 + ty * 8 + 4);
                const float4 b0 = *(const float4*)(Bs + kk * 128 + tx * 8);
                const float4 b1 = *(const float4*)(Bs + kk * 128 + tx * 8 + 4);
                const float a[8] = {a0.x,a0.y,a0.z,a0.w,a1.x,a1.y,a1.z,a1.w};
                const float bb[8] = {b0.x,b0.y,b0.z,b0.w,b1.x,b1.y,b1.z,b1.w};
                #pragma unroll
                for (int i = 0; i < 8; i++)
                    #pragma unroll
                    for (int j = 0; j < 8; j++)
                        acc[i][j] = fmaf(a[i], bb[j], acc[i][j]);
            }
        }
        const float4 en0 = *(const float4*)(enorm + c0 + tx * 8);
        const float4 en1 = *(const float4*)(enorm + c0 + tx * 8 + 4);
        const float en[8] = {en0.x,en0.y,en0.z,en0.w,en1.x,en1.y,en1.z,en1.w};
        #pragma unroll
        for (int j = 0; j < 8; j++) {
            const int c = c0 + tx * 8 + j;
            #pragma unroll
            for (int i = 0; i < 8; i++) {
                const float dist = fmaf(-2.0f, acc[i][j], en[j]);
                if (dist < best[i]) { best[i] = dist; bidx[i] = c; }
            }
        }
    }
    __syncthreads();
    float* rmin = smem;
    int* ridx = (int*)(smem + 2048);
    #pragma unroll
    for (int i = 0; i < 8; i++) {
        const int r = ty * 8 + i;
        rmin[r * 16 + tx] = best[i];
        ridx[r * 16 + tx] = bidx[i];
    }
    __syncthreads();
    if (tid < 128) {
        const int r = tid;
        float m = rmin[r * 16]; int mi = ridx[r * 16];
        #pragma unroll
        for (int tt = 1; tt < 16; tt++) {
            const float v = rmin[r * 16 + tt];
            const int vi = ridx[r * 16 + tt];
            if (v < m || (v == m && vi < mi)) { m = v; mi = vi; }
        }
        const int p = p0 + r;
        idx_out[p] = mi;
        idx_out_f[p] = (float)mi;
        atomicAdd(&counts[mi], 1.0f);
    }
}

extern "C" void kernel_launch(void* const* d_in, const int* in_sizes, int n_in,
                              void* d_out, int out_size, void* d_ws, size_t ws_size,
                              hipStream_t stream) {
    const float* z       = (const float*)d_in[0];
    const float* emb     = (const float*)d_in[1];
    const float* ema_cs  = (const float*)d_in[2];
    const float* ema_emb = (const float*)d_in[3];
    float* out = (float*)d_out;
    float* ws  = (float*)d_ws;

    int*   ws_idx    = (int*)(ws + WS_IDX);
    float* ws_counts = ws + WS_COUNTS;
    int*   ws_rcnt   = (int*)(ws + WS_RCNT);
    float* ws_lossp  = ws + WS_LOSSP;
    float* ws_enorm  = ws + WS_ENORM;
    int*   ws_rlist  = (int*)(ws + WS_RLIST);
    unsigned short* ws_eaug = (unsigned short*)(ws + WS_EAUG);

    // zero counts + rescue counter
    hipMemsetAsync(ws_counts, 0, 1025 * sizeof(float), stream);
    hipLaunchKernelGGL(enorm_kernel, dim3(KC), dim3(256), 0, stream, emb, ws_enorm);

    if (ws_size >= (size_t)WS_NEED_FLOATS * sizeof(float)) {
        hipLaunchKernelGGL(convert_emb_kernel, dim3(64), dim3(256), 0, stream, emb, ws_eaug);
        hipLaunchKernelGGL(gemm_argmin_kernel, dim3(1024), dim3(512), 0, stream,
                           z, ws_eaug, ws_enorm, ws_idx, out + OUT_IDX,
                           ws_counts, ws_rcnt, ws_rlist);
        hipLaunchKernelGGL(rescue_kernel, dim3(512), dim3(256), 0, stream,
                           z, emb, ws_enorm, ws_rcnt, ws_rlist,
                           ws_idx, out + OUT_IDX, ws_counts);
    } else {
        hipLaunchKernelGGL(dist_argmin_kernel, dim3(NP / 128), dim3(256), 0, stream,
                           z, emb, ws_enorm, ws_idx, out + OUT_IDX, ws_counts);
    }

    hipLaunchKernelGGL(dwq_kernel, dim3(DD), dim3(512), 0, stream,
                       z, emb, ws_idx, ema_emb, out, out + OUT_EMA, ws_lossp);
    hipLaunchKernelGGL(finalize_kernel, dim3(4), dim3(256), 0, stream,
                       ema_cs, ws_counts, ws_lossp, out);
}